// Round 7
// baseline (467.604 us; speedup 1.0000x reference)
//
#include <hip/hip_runtime.h>
#include <hip/hip_bf16.h>
#include <math.h>

typedef __bf16 bf16_t;
typedef bf16_t bf16x4 __attribute__((ext_vector_type(4)));
typedef bf16_t bf16x8 __attribute__((ext_vector_type(8)));
typedef float f32x4 __attribute__((ext_vector_type(4)));

#define Bsz 16
#define LCc 512
#define LQq 64
#define Hd 256
#define Dd 1024
#define DFFd 512
#define DP1 1025
#define KP 1152      // padded contraction dim, 18 tiles of 64 (EVEN -> no tail)
#define NROW 8192
#define YC 1536

// ---- workspace layout (bytes). T aliases the early-dead region. ----
#define OFF_T    0L          // 24576*1152*2 = 56623104
#define OFF_QW2  0L
#define OFF_MROW 4096L
#define OFF_Q2C  36864L
#define OFF_C2Q  53248L      // 8388608
#define OFF_XB   8441856L    // 16777216
#define OFF_HBUF 25219072L   // 16777216
#define OFF_W1C  41996288L   // 2097152
#define OFF_W2C  44093440L   // 2097152 (ends 46190592 < 56623104)
#define OFF_S1   56623104L   // 18874368
#define OFF_E1   75497472L   // 18874368
#define OFF_WBT  94371840L   // 3072*1152*2 = 7077888 ; end = 101449728

static __device__ __forceinline__ void gload_lds16(const void* g, void* l) {
    __builtin_amdgcn_global_load_lds(
        (const __attribute__((address_space(1))) void*)g,
        (__attribute__((address_space(3))) void*)l, 16, 0, 0);
}

// ---------- qw2[b,j] = dot(ques[b,j,:], w2) ----------
__global__ __launch_bounds__(256) void k_qw2(const float* __restrict__ ques,
                                             const float* __restrict__ wsim,
                                             float* __restrict__ qw2) {
    int row = blockIdx.x * 4 + (threadIdx.x >> 6);
    int lane = threadIdx.x & 63;
    float4 q = *(const float4*)&ques[(long)row * Hd + lane * 4];
    float4 w = *(const float4*)&wsim[Hd + lane * 4];
    float p = q.x * w.x + q.y * w.y + q.z * w.z + q.w * w.w;
#pragma unroll
    for (int o = 32; o >= 1; o >>= 1) p += __shfl_xor(p, o, 64);
    if (lane == 0) qw2[row] = p;
}

// ---------- weight transpose f32 [K][N] -> bf16 [N][K], z-pair merged ----------
__global__ __launch_bounds__(256) void k_wtrans2(const float* __restrict__ in0,
                                                 const float* __restrict__ in1,
                                                 bf16_t* __restrict__ out,
                                                 int K, int N) {
    __shared__ float tile[32][33];
    const float* in = blockIdx.z ? in1 : in0;
    bf16_t* o = out + (long)blockIdx.z * K * N;
    int k0 = blockIdx.x * 32, n0 = blockIdx.y * 32;
    int r = threadIdx.x >> 5, c = threadIdx.x & 31;
#pragma unroll
    for (int rr = 0; rr < 32; rr += 8)
        tile[r + rr][c] = in[(long)(k0 + r + rr) * N + n0 + c];
    __syncthreads();
#pragma unroll
    for (int rr = 0; rr < 32; rr += 8)
        o[(long)(n0 + r + rr) * K + k0 + c] = (bf16_t)tile[c][r + rr];
}

// ---------- Wbt[c*1024+i][j] = Wb[i,c,j], bf16, [3072][1152], cols>=1025 zero ----------
__global__ __launch_bounds__(256) void k_wb(const float* __restrict__ Wb,
                                            bf16_t* __restrict__ Wbt) {
    int rw = blockIdx.x;            // c*1024 + i
    int c = rw >> 10, i = rw & 1023;
    int tid = threadIdx.x;
    const float* src = Wb + ((long)i * 3 + c) * DP1;
    bf16_t* orow = Wbt + (long)rw * KP;
#pragma unroll
    for (int p = 0; p < 2; p++) {
        int j4 = tid + p * 256;
        if (j4 < KP / 4) {
            int j = j4 * 4;
            float x = (j + 0 < DP1) ? src[j + 0] : 0.f;
            float y = (j + 1 < DP1) ? src[j + 1] : 0.f;
            float z = (j + 2 < DP1) ? src[j + 2] : 0.f;
            float w = (j + 3 < DP1) ? src[j + 3] : 0.f;
            bf16x4 bv = {(bf16_t)x, (bf16_t)y, (bf16_t)z, (bf16_t)w};
            *(bf16x4*)&orow[j] = bv;
        }
    }
}

// ---------- init cols [1024..1151] of s1,e1: col1024=1, rest 0 ----------
__global__ __launch_bounds__(256) void k_initse(bf16_t* __restrict__ s1,
                                                bf16_t* __restrict__ e1) {
    int idx = blockIdx.x * 256 + threadIdx.x;   // 8192*128
    long r = idx >> 7; int cc = idx & 127;
    bf16_t v = (bf16_t)(cc == 0 ? 1.0f : 0.0f);
    s1[r * KP + 1024 + cc] = v;
    e1[r * KP + 1024 + cc] = v;
}

// ---------- attention: sim -> softmax_j -> c2q, rowmax -> mrow ----------
__global__ __launch_bounds__(256) void k_attn(const float* __restrict__ ctx,
                                              const float* __restrict__ ques,
                                              const float* __restrict__ wsim,
                                              const float* __restrict__ qw2,
                                              float* __restrict__ c2q,
                                              float* __restrict__ mrow) {
    __shared__ bf16x4 qlds[LQq * 64];
    __shared__ float cw3s[4][Hd];
    __shared__ float awave[4][LQq];
    int b = blockIdx.x >> 5;
    int itile = blockIdx.x & 31;
    int tid = threadIdx.x, wid = tid >> 6, lane = tid & 63;
#pragma unroll
    for (int p = 0; p < 16; p++) {
        int s = tid + p * 256;
        int j = s >> 6, h4s = s & 63;
        int h4 = h4s ^ (j & 15);
        float4 v = *(const float4*)&ques[((long)b * LQq + j) * Hd + h4 * 4];
        bf16x4 bv = {(bf16_t)v.x, (bf16_t)v.y, (bf16_t)v.z, (bf16_t)v.w};
        qlds[s] = bv;
    }
    float qw2r = qw2[b * LQq + lane];
    float4 w1v = *(const float4*)&wsim[lane * 4];
    float4 w3v = *(const float4*)&wsim[2 * Hd + lane * 4];
    __syncthreads();
    for (int rr = 0; rr < 4; rr++) {
        int i = itile * 16 + wid * 4 + rr;
        float4 cv = *(const float4*)&ctx[((long)b * LCc + i) * Hd + lane * 4];
        float cw1p = cv.x * w1v.x + cv.y * w1v.y + cv.z * w1v.z + cv.w * w1v.w;
        float4 c3;
        c3.x = cv.x * w3v.x; c3.y = cv.y * w3v.y;
        c3.z = cv.z * w3v.z; c3.w = cv.w * w3v.w;
        *(float4*)&cw3s[wid][lane * 4] = c3;
#pragma unroll
        for (int o = 32; o >= 1; o >>= 1) cw1p += __shfl_xor(cw1p, o, 64);
        __syncthreads();
        float s = cw1p + qw2r;
#pragma unroll 8
        for (int h4 = 0; h4 < 64; h4++) {
            float4 c3v = *(const float4*)&cw3s[wid][h4 * 4];
            bf16x4 qb = qlds[lane * 64 + (h4 ^ (lane & 15))];
            s += c3v.x * (float)qb[0] + c3v.y * (float)qb[1]
               + c3v.z * (float)qb[2] + c3v.w * (float)qb[3];
        }
        float mx = s;
#pragma unroll
        for (int o = 32; o >= 1; o >>= 1) mx = fmaxf(mx, __shfl_xor(mx, o, 64));
        if (lane == 0) mrow[b * LCc + i] = mx;
        float pe = __expf(s - mx);
        float den = pe;
#pragma unroll
        for (int o = 32; o >= 1; o >>= 1) den += __shfl_xor(den, o, 64);
        awave[wid][lane] = pe / den;
        __syncthreads();
        float4 accv = {0.f, 0.f, 0.f, 0.f};
#pragma unroll 8
        for (int j = 0; j < 64; j++) {
            float aj = awave[wid][j];
            bf16x4 qb = qlds[j * 64 + (lane ^ (j & 15))];
            accv.x = fmaf(aj, (float)qb[0], accv.x);
            accv.y = fmaf(aj, (float)qb[1], accv.y);
            accv.z = fmaf(aj, (float)qb[2], accv.z);
            accv.w = fmaf(aj, (float)qb[3], accv.w);
        }
        *(float4*)&c2q[((long)b * LCc + i) * Hd + lane * 4] = accv;
        __syncthreads();
    }
}

// ---------- q2c: 128 blocks = 16 b x 8 h-chunks ----------
__global__ __launch_bounds__(256) void k_q2c(const float* __restrict__ ctx,
                                             const float* __restrict__ mrow,
                                             float* __restrict__ q2c) {
    __shared__ float wbuf[LCc];
    __shared__ float red[8];
    __shared__ float part[8][32];
    int blk = blockIdx.x;
    int b = blk >> 3, hc = blk & 7;
    int tid = threadIdx.x;
    float v0 = mrow[b * LCc + tid], v1 = mrow[b * LCc + 256 + tid];
    float m = fmaxf(v0, v1);
#pragma unroll
    for (int o = 32; o >= 1; o >>= 1) m = fmaxf(m, __shfl_xor(m, o, 64));
    if ((tid & 63) == 0) red[tid >> 6] = m;
    __syncthreads();
    float M = fmaxf(fmaxf(red[0], red[1]), fmaxf(red[2], red[3]));
    float e0 = __expf(v0 - M), e1v = __expf(v1 - M);
    float sm = e0 + e1v;
#pragma unroll
    for (int o = 32; o >= 1; o >>= 1) sm += __shfl_xor(sm, o, 64);
    if ((tid & 63) == 0) red[4 + (tid >> 6)] = sm;
    __syncthreads();
    float S = red[4] + red[5] + red[6] + red[7];
    wbuf[tid] = e0 / S;
    wbuf[tid + 256] = e1v / S;
    __syncthreads();
    int ig = tid >> 5, h31 = tid & 31;
    int h = hc * 32 + h31;
    float acc = 0.f;
#pragma unroll 4
    for (int ii = 0; ii < 64; ii++) {
        int i = ig * 64 + ii;
        acc = fmaf(wbuf[i], ctx[((long)b * LCc + i) * Hd + h], acc);
    }
    part[ig][h31] = acc;
    __syncthreads();
    if (tid < 32) {
        float s = 0.f;
#pragma unroll
        for (int k = 0; k < 8; k++) s += part[k][tid];
        q2c[b * Hd + hc * 32 + tid] = s;
    }
}

// ---------- x = [ctx, c2q, ctx*c2q, ctx*q2c] -> bf16 [8192][1024] ----------
__global__ __launch_bounds__(256) void k_buildx(const float* __restrict__ ctx,
                                                const float* __restrict__ c2q,
                                                const float* __restrict__ q2c,
                                                bf16_t* __restrict__ xb) {
    long r = blockIdx.x;
    int b = (int)(r >> 9);
    int tid = threadIdx.x;
    int sec = tid >> 6, h4 = tid & 63;
    float4 cv = *(const float4*)&ctx[r * Hd + h4 * 4];
    float4 v;
    if (sec == 0) {
        v = cv;
    } else if (sec == 1) {
        v = *(const float4*)&c2q[r * Hd + h4 * 4];
    } else if (sec == 2) {
        float4 q = *(const float4*)&c2q[r * Hd + h4 * 4];
        v.x = cv.x * q.x; v.y = cv.y * q.y; v.z = cv.z * q.z; v.w = cv.w * q.w;
    } else {
        float4 q = *(const float4*)&q2c[b * Hd + h4 * 4];
        v.x = cv.x * q.x; v.y = cv.y * q.y; v.z = cv.z * q.z; v.w = cv.w * q.w;
    }
    bf16x4 bv = {(bf16_t)v.x, (bf16_t)v.y, (bf16_t)v.z, (bf16_t)v.w};
    *(bf16x4*)&xb[r * Dd + sec * Hd + h4 * 4] = bv;
}

// ---------- g-column + T pad-zero ----------
__global__ __launch_bounds__(256) void k_gcol(const bf16_t* __restrict__ e1,
                                              const float* __restrict__ Wb,
                                              bf16_t* __restrict__ T) {
    int tid = threadIdx.x;
    int wv = tid >> 6, lane = tid & 63;
    long r = (long)blockIdx.x * 4 + wv;
    bf16x8 ea = *(const bf16x8*)&e1[r * KP + lane * 16];
    bf16x8 eb = *(const bf16x8*)&e1[r * KP + lane * 16 + 8];
    const float* wr0 = Wb + (long)3072 * DP1;   // row block i=1024
#pragma unroll
    for (int c = 0; c < 3; c++) {
        const float* wr = wr0 + (long)c * DP1 + lane * 16;
        float acc = 0.f;
#pragma unroll
        for (int k = 0; k < 8; k++) {
            acc = fmaf((float)ea[k], wr[k], acc);
            acc = fmaf((float)eb[k], wr[8 + k], acc);
        }
#pragma unroll
        for (int o = 32; o >= 1; o >>= 1) acc += __shfl_xor(acc, o, 64);
        long rowb = (r * 3 + c) * (long)KP;
        if (lane == 0)
            T[rowb + 1024] = (bf16_t)(acc + wr0[(long)c * DP1 + 1024]);
        for (int jj = 1025 + lane; jj < KP; jj += 64)
            T[rowb + jj] = (bf16_t)0.f;
    }
}

// ---------- unified 8-phase counted-vmcnt GEMM: tile 256 x (64*NFR), BK=64 ----------
// MODE 0 (FFW1): A=xb lda1024, B=W1c ldb1024, NT=16, NFR=2, grid 256 (32bx x 8by)
// MODE 1 (FFW2): A=hbuf+z*512, B=W2c+z*512K, NT=8, NFR=4, grid 256
// MODE 2 (Tcore): A=e1, B=Wbt, ld KP, NT=18, NFR=6, grid 256 (32bx x 8by, 1 round)
// MODE 3 (out):  A=s1_z, B=T_z, ld KP, NT=18, NFR=3, grid 256 (2bx x 8yy x 16zz)
template <int NT, int NFR, int MODE>
__global__ __launch_bounds__(512) void gemm8p(
    const bf16_t* __restrict__ A, const bf16_t* __restrict__ B,
    const float* __restrict__ b0, const float* __restrict__ b1,
    void* __restrict__ C0, void* __restrict__ C1) {
    constexpr int LDA = (MODE <= 1) ? 1024 : KP;
    constexpr int LDB = (MODE == 0) ? 1024 : (MODE == 1) ? 512 : KP;
    constexpr int BEn = (NFR + 1) / 2;
    constexpr int BOn = NFR / 2;
    constexpr int NCOL = 64 * NFR;
    __shared__ char smem[65536 + NFR * 16384];   // A 2x16K dbuf | B 2xNFR*8K dbuf
    int tid = threadIdx.x;
    int wg = blockIdx.x;
    int xcd = wg & 7, idx = wg >> 3;
    int bx, by, z = 0;
    if (MODE == 0) {
        bx = (xcd & 3) * 8 + (idx & 7); by = (xcd >> 2) * 4 + (idx >> 3);
    } else if (MODE == 1) {
        z = idx >> 4; bx = (xcd & 3) * 8 + (idx & 7); by = (xcd >> 2) * 2 + ((idx >> 3) & 1);
    } else if (MODE == 2) {
        bx = (xcd & 3) * 8 + (idx & 7); by = (xcd >> 2) * 4 + (idx >> 3);
    } else {
        z = xcd * 2 + (idx >> 4); bx = idx & 1; by = (idx >> 1) & 7;
    }
    const bf16_t* At;
    const bf16_t* Bt;
    if (MODE == 0) {
        At = A + (long)bx * 256 * LDA;            Bt = B + (long)by * NCOL * LDB;
    } else if (MODE == 1) {
        At = A + (long)z * 512 + (long)bx * 256 * LDA;
        Bt = B + (long)z * 524288 + (long)by * NCOL * LDB;
    } else if (MODE == 2) {
        At = A + (long)bx * 256 * LDA;            Bt = B + (long)by * NCOL * LDB;
    } else {
        At = A + ((long)z * 512 + bx * 256) * LDA;
        Bt = B + ((long)z * 1536 + by * NCOL) * LDB;
    }
    int lane = tid & 63, wv = tid >> 6, wm = wv >> 2, wn = wv & 3;
    int fr = lane & 15, kg = lane >> 4;
    int row0 = tid >> 3, sc0 = (tid & 7) ^ (row0 & 7);
    int q1 = tid + 512;
    int row1 = q1 >> 3, sc1 = (q1 & 7) ^ (row1 & 7);

    auto stageA = [&](int half, int tile) {
        int ts = tile <= NT - 1 ? tile : NT - 1;   // clamp source
        int buf = tile & 1;
        long rb = (long)half * 128;
        const bf16_t* g0 = At + (rb + row0) * LDA + ts * 64 + sc0 * 8;
        const bf16_t* g1 = At + (rb + row1) * LDA + ts * 64 + sc1 * 8;
        char* l = smem + buf * 32768 + half * 16384;
        gload_lds16(g0, l + tid * 16);
        gload_lds16(g1, l + 8192 + tid * 16);
    };
    auto stageB = [&](int j, int tile) {          // one 64-row call
        int ts = tile <= NT - 1 ? tile : NT - 1;
        int buf = tile & 1;
        const bf16_t* g0 = Bt + (long)(j * 64 + row0) * LDB + ts * 64 + sc0 * 8;
        char* l = smem + 65536 + buf * (NFR * 8192) + j * 8192;
        gload_lds16(g0, l + tid * 16);
    };
    auto RDA = [&](int buf, int h, int m, int kk) -> bf16x8 {
        int row = wm * 128 + h * 64 + m * 16 + fr;
        int c16 = kk * 4 + kg;
        int off = buf * 32768 + row * 128 + ((c16 ^ (row & 7)) << 4);
        return *(const bf16x8*)(smem + off);
    };
    auto RDB = [&](int buf, int n, int kk) -> bf16x8 {
        int row = wn * (16 * NFR) + n * 16 + fr;
        int c16 = kk * 4 + kg;
        int off = 65536 + buf * (NFR * 8192) + row * 128 + ((c16 ^ (row & 7)) << 4);
        return *(const bf16x8*)(smem + off);
    };

    f32x4 acc[8][NFR] = {};

    // prologue: T0 A(4 calls) + T0 B(NFR) + T1 A(4); leave last 4 (T1-A) in flight
    stageA(0, 0); stageA(1, 0);
#pragma unroll
    for (int j = 0; j < NFR; j++) stageB(j, 0);
    stageA(0, 1); stageA(1, 1);
    asm volatile("s_waitcnt vmcnt(4)" ::: "memory");
    __builtin_amdgcn_s_barrier();

    auto doTile = [&](int buf, int sB, int sA) {
        bf16x8 aL[4][2], aH[4][2], bE[BEn][2], bO[BOn][2];
        // phase a: read A-h0 + B-even, stage B[0..BEn), MFMA (h0, even)
#pragma unroll
        for (int m = 0; m < 4; m++)
#pragma unroll
            for (int k = 0; k < 2; k++) aL[m][k] = RDA(buf, 0, m, k);
#pragma unroll
        for (int n = 0; n < BEn; n++)
#pragma unroll
            for (int k = 0; k < 2; k++) bE[n][k] = RDB(buf, n, k);
#pragma unroll
        for (int j = 0; j < BEn; j++) stageB(j, sB);
        __builtin_amdgcn_s_barrier();
        __builtin_amdgcn_s_setprio(1);
#pragma unroll
        for (int m = 0; m < 4; m++)
#pragma unroll
            for (int n = 0; n < BEn; n++)
#pragma unroll
                for (int k = 0; k < 2; k++)
                    acc[m][n] = __builtin_amdgcn_mfma_f32_16x16x32_bf16(
                        aL[m][k], bE[n][k], acc[m][n], 0, 0, 0);
        __builtin_amdgcn_s_setprio(0);
        __builtin_amdgcn_s_barrier();
        // phase b: read B-odd, stage B[BEn..NFR), MFMA (h0, odd)
#pragma unroll
        for (int n = 0; n < BOn; n++)
#pragma unroll
            for (int k = 0; k < 2; k++) bO[n][k] = RDB(buf, BEn + n, k);
#pragma unroll
        for (int j = BEn; j < NFR; j++) stageB(j, sB);
        __builtin_amdgcn_s_barrier();
        __builtin_amdgcn_s_setprio(1);
#pragma unroll
        for (int m = 0; m < 4; m++)
#pragma unroll
            for (int n = 0; n < BOn; n++)
#pragma unroll
                for (int k = 0; k < 2; k++)
                    acc[m][BEn + n] = __builtin_amdgcn_mfma_f32_16x16x32_bf16(
                        aL[m][k], bO[n][k], acc[m][BEn + n], 0, 0, 0);
        __builtin_amdgcn_s_setprio(0);
        __builtin_amdgcn_s_barrier();
        // phase c: read A-h1, stage A0(sA), MFMA (h1, even)
#pragma unroll
        for (int m = 0; m < 4; m++)
#pragma unroll
            for (int k = 0; k < 2; k++) aH[m][k] = RDA(buf, 1, m, k);
        stageA(0, sA);
        __builtin_amdgcn_s_barrier();
        __builtin_amdgcn_s_setprio(1);
#pragma unroll
        for (int m = 0; m < 4; m++)
#pragma unroll
            for (int n = 0; n < BEn; n++)
#pragma unroll
                for (int k = 0; k < 2; k++)
                    acc[4 + m][n] = __builtin_amdgcn_mfma_f32_16x16x32_bf16(
                        aH[m][k], bE[n][k], acc[4 + m][n], 0, 0, 0);
        __builtin_amdgcn_s_setprio(0);
        __builtin_amdgcn_s_barrier();
        // phase d: stage A1(sA), MFMA (h1, odd), counted vmcnt, barrier
        stageA(1, sA);
        __builtin_amdgcn_s_barrier();
        __builtin_amdgcn_s_setprio(1);
#pragma unroll
        for (int m = 0; m < 4; m++)
#pragma unroll
            for (int n = 0; n < BOn; n++)
#pragma unroll
                for (int k = 0; k < 2; k++)
                    acc[4 + m][BEn + n] = __builtin_amdgcn_mfma_f32_16x16x32_bf16(
                        aH[m][k], bO[n][k], acc[4 + m][BEn + n], 0, 0, 0);
        __builtin_amdgcn_s_setprio(0);
        asm volatile("s_waitcnt vmcnt(4)" ::: "memory");
        __builtin_amdgcn_s_barrier();
    };

    for (int it = 0; it < NT / 2; ++it) {
        int t = 2 * it;
        doTile(0, t + 1, t + 2);
        doTile(1, t + 2, t + 3);
    }

    // epilogue
#pragma unroll
    for (int mf = 0; mf < 8; mf++) {
#pragma unroll
        for (int g = 0; g < 4; g++) {
            int rloc = wm * 128 + mf * 16 + kg * 4 + g;
            long r = (long)bx * 256 + rloc;
#pragma unroll
            for (int nf = 0; nf < NFR; nf++) {
                int col = wn * (16 * NFR) + nf * 16 + fr;
                float v = acc[mf][nf][g];
                if (MODE == 0) {
                    int colg = by * NCOL + col;
                    v += (colg < 512) ? b0[colg] : b1[colg - 512];
                    v = fmaxf(v, 0.f);
                    ((bf16_t*)C0)[r * 1024 + colg] = (bf16_t)v;
                } else if (MODE == 1) {
                    int colg = by * NCOL + col;
                    v += z ? b1[colg] : b0[colg];
                    ((bf16_t*)(z ? C1 : C0))[r * (long)KP + colg] = (bf16_t)v;
                } else if (MODE == 2) {
                    int colg = by * NCOL + col;
                    int cls = colg >> 10, i = colg & 1023;
                    ((bf16_t*)C0)[(r * 3 + cls) * (long)KP + i] = (bf16_t)v;
                } else {
                    int colg = by * NCOL + col;
                    ((float*)C0)[(long)z * (512L * YC) + r * YC + colg] = v;
                }
            }
        }
    }
}

extern "C" void kernel_launch(void* const* d_in, const int* in_sizes, int n_in,
                              void* d_out, int out_size, void* d_ws, size_t ws_size,
                              hipStream_t stream) {
    const float* ctx  = (const float*)d_in[0];
    const float* ques = (const float*)d_in[1];
    const float* wsim = (const float*)d_in[2];
    const float* W1s  = (const float*)d_in[3];
    const float* b1s  = (const float*)d_in[4];
    const float* W2s  = (const float*)d_in[5];
    const float* b2s  = (const float*)d_in[6];
    const float* W1e  = (const float*)d_in[7];
    const float* b1e  = (const float*)d_in[8];
    const float* W2e  = (const float*)d_in[9];
    const float* b2e  = (const float*)d_in[10];
    const float* Wb   = (const float*)d_in[11];

    char* ws = (char*)d_ws;
    float*  qw2  = (float*)(ws + OFF_QW2);
    float*  mrow = (float*)(ws + OFF_MROW);
    float*  q2c  = (float*)(ws + OFF_Q2C);
    float*  c2q  = (float*)(ws + OFF_C2Q);
    bf16_t* xb   = (bf16_t*)(ws + OFF_XB);
    bf16_t* hbuf = (bf16_t*)(ws + OFF_HBUF);
    bf16_t* W1c  = (bf16_t*)(ws + OFF_W1C);
    bf16_t* W2c  = (bf16_t*)(ws + OFF_W2C);
    bf16_t* T    = (bf16_t*)(ws + OFF_T);
    bf16_t* s1   = (bf16_t*)(ws + OFF_S1);
    bf16_t* e1   = (bf16_t*)(ws + OFF_E1);
    bf16_t* Wbt  = (bf16_t*)(ws + OFF_WBT);

    // weight prep + attention front-end
    k_qw2<<<256, 256, 0, stream>>>(ques, wsim, qw2);
    k_wtrans2<<<dim3(32, 16, 2), 256, 0, stream>>>(W1s, W1e, W1c, 1024, 512);
    k_wtrans2<<<dim3(16, 32, 2), 256, 0, stream>>>(W2s, W2e, W2c, 512, 1024);
    k_wb<<<3072, 256, 0, stream>>>(Wb, Wbt);
    k_attn<<<Bsz * 32, 256, 0, stream>>>(ctx, ques, wsim, qw2, c2q, mrow);
    k_q2c<<<128, 256, 0, stream>>>(ctx, mrow, q2c);
    k_buildx<<<NROW, 256, 0, stream>>>(ctx, c2q, q2c, xb);
    k_initse<<<4096, 256, 0, stream>>>(s1, e1);

    // FFW1: hbuf = relu(x@[W1s|W1e] + [b1s|b1e])  (256x128 tiles, grid 256)
    gemm8p<16, 2, 0><<<256, 512, 0, stream>>>(xb, W1c, b1s, b1e, hbuf, nullptr);
    // FFW2: {s1,e1} = h_z @ W2z + b2z             (256x256 tiles, grid 256)
    gemm8p<8, 4, 1><<<256, 512, 0, stream>>>(hbuf, W2c, b2s, b2e, s1, e1);
    // g-column of T (i = 1024) + zero T pad cols
    k_gcol<<<2048, 256, 0, stream>>>(e1, Wb, T);
    // T core: [8192x3072] = e1 @ Wbt^T            (256x384 tiles, grid 256 = 1 round)
    gemm8p<18, 6, 2><<<256, 512, 0, stream>>>(e1, Wbt, nullptr, nullptr, T, nullptr);
    // out = s1 @ T^T per batch                    (256x192 tiles, grid 256)
    gemm8p<18, 3, 3><<<256, 512, 0, stream>>>(s1, T, nullptr, nullptr, d_out, nullptr);
}

// Round 8
// 296.409 us; speedup vs baseline: 1.5776x; 1.5776x over previous
//
#include <hip/hip_runtime.h>
#include <hip/hip_bf16.h>
#include <math.h>

typedef __bf16 bf16_t;
typedef bf16_t bf16x4 __attribute__((ext_vector_type(4)));
typedef bf16_t bf16x8 __attribute__((ext_vector_type(8)));
typedef float f32x4 __attribute__((ext_vector_type(4)));

#define Bsz 16
#define LCc 512
#define LQq 64
#define Hd 256
#define Dd 1024
#define DFFd 512
#define DP1 1025
#define KP 1152      // padded contraction dim, 18 tiles of 64 (EVEN -> no tail)
#define NROW 8192
#define YC 1536

// ---- workspace layout (bytes). T aliases the early-dead region. ----
#define OFF_T    0L          // 24576*1152*2 = 56623104
#define OFF_QW2  0L
#define OFF_MROW 4096L
#define OFF_Q2C  36864L
#define OFF_C2Q  53248L      // 8388608
#define OFF_XB   8441856L    // 16777216
#define OFF_HBUF 25219072L   // 16777216
#define OFF_W1C  41996288L   // 2097152
#define OFF_W2C  44093440L   // 2097152 (ends 46190592 < 56623104)
#define OFF_S1   56623104L   // 18874368
#define OFF_E1   75497472L   // 18874368
#define OFF_WBT  94371840L   // 3072*1152*2 = 7077888 ; end = 101449728

static __device__ __forceinline__ void gload_lds16(const void* g, void* l) {
    __builtin_amdgcn_global_load_lds(
        (const __attribute__((address_space(1))) void*)g,
        (__attribute__((address_space(3))) void*)l, 16, 0, 0);
}

// ---------- qw2[b,j] = dot(ques[b,j,:], w2) ----------
__global__ __launch_bounds__(256) void k_qw2(const float* __restrict__ ques,
                                             const float* __restrict__ wsim,
                                             float* __restrict__ qw2) {
    int row = blockIdx.x * 4 + (threadIdx.x >> 6);
    int lane = threadIdx.x & 63;
    float4 q = *(const float4*)&ques[(long)row * Hd + lane * 4];
    float4 w = *(const float4*)&wsim[Hd + lane * 4];
    float p = q.x * w.x + q.y * w.y + q.z * w.z + q.w * w.w;
#pragma unroll
    for (int o = 32; o >= 1; o >>= 1) p += __shfl_xor(p, o, 64);
    if (lane == 0) qw2[row] = p;
}

// ---------- weight transpose f32 [K][N] -> bf16 [N][K], z-pair merged ----------
__global__ __launch_bounds__(256) void k_wtrans2(const float* __restrict__ in0,
                                                 const float* __restrict__ in1,
                                                 bf16_t* __restrict__ out,
                                                 int K, int N) {
    __shared__ float tile[32][33];
    const float* in = blockIdx.z ? in1 : in0;
    bf16_t* o = out + (long)blockIdx.z * K * N;
    int k0 = blockIdx.x * 32, n0 = blockIdx.y * 32;
    int r = threadIdx.x >> 5, c = threadIdx.x & 31;
#pragma unroll
    for (int rr = 0; rr < 32; rr += 8)
        tile[r + rr][c] = in[(long)(k0 + r + rr) * N + n0 + c];
    __syncthreads();
#pragma unroll
    for (int rr = 0; rr < 32; rr += 8)
        o[(long)(n0 + r + rr) * K + k0 + c] = (bf16_t)tile[c][r + rr];
}

// ---------- Wbt[c*1024+i][j] = Wb[i,c,j], bf16, [3072][1152], cols>=1025 zero ----------
__global__ __launch_bounds__(256) void k_wb(const float* __restrict__ Wb,
                                            bf16_t* __restrict__ Wbt) {
    int rw = blockIdx.x;            // c*1024 + i
    int c = rw >> 10, i = rw & 1023;
    int tid = threadIdx.x;
    const float* src = Wb + ((long)i * 3 + c) * DP1;
    bf16_t* orow = Wbt + (long)rw * KP;
#pragma unroll
    for (int p = 0; p < 2; p++) {
        int j4 = tid + p * 256;
        if (j4 < KP / 4) {
            int j = j4 * 4;
            float x = (j + 0 < DP1) ? src[j + 0] : 0.f;
            float y = (j + 1 < DP1) ? src[j + 1] : 0.f;
            float z = (j + 2 < DP1) ? src[j + 2] : 0.f;
            float w = (j + 3 < DP1) ? src[j + 3] : 0.f;
            bf16x4 bv = {(bf16_t)x, (bf16_t)y, (bf16_t)z, (bf16_t)w};
            *(bf16x4*)&orow[j] = bv;
        }
    }
}

// ---------- init cols [1024..1151] of s1,e1: col1024=1, rest 0 ----------
__global__ __launch_bounds__(256) void k_initse(bf16_t* __restrict__ s1,
                                                bf16_t* __restrict__ e1) {
    int idx = blockIdx.x * 256 + threadIdx.x;   // 8192*128
    long r = idx >> 7; int cc = idx & 127;
    bf16_t v = (bf16_t)(cc == 0 ? 1.0f : 0.0f);
    s1[r * KP + 1024 + cc] = v;
    e1[r * KP + 1024 + cc] = v;
}

// ---------- attention: sim -> softmax_j -> c2q, rowmax -> mrow ----------
__global__ __launch_bounds__(256) void k_attn(const float* __restrict__ ctx,
                                              const float* __restrict__ ques,
                                              const float* __restrict__ wsim,
                                              const float* __restrict__ qw2,
                                              float* __restrict__ c2q,
                                              float* __restrict__ mrow) {
    __shared__ bf16x4 qlds[LQq * 64];
    __shared__ float cw3s[4][Hd];
    __shared__ float awave[4][LQq];
    int b = blockIdx.x >> 5;
    int itile = blockIdx.x & 31;
    int tid = threadIdx.x, wid = tid >> 6, lane = tid & 63;
#pragma unroll
    for (int p = 0; p < 16; p++) {
        int s = tid + p * 256;
        int j = s >> 6, h4s = s & 63;
        int h4 = h4s ^ (j & 15);
        float4 v = *(const float4*)&ques[((long)b * LQq + j) * Hd + h4 * 4];
        bf16x4 bv = {(bf16_t)v.x, (bf16_t)v.y, (bf16_t)v.z, (bf16_t)v.w};
        qlds[s] = bv;
    }
    float qw2r = qw2[b * LQq + lane];
    float4 w1v = *(const float4*)&wsim[lane * 4];
    float4 w3v = *(const float4*)&wsim[2 * Hd + lane * 4];
    __syncthreads();
    for (int rr = 0; rr < 4; rr++) {
        int i = itile * 16 + wid * 4 + rr;
        float4 cv = *(const float4*)&ctx[((long)b * LCc + i) * Hd + lane * 4];
        float cw1p = cv.x * w1v.x + cv.y * w1v.y + cv.z * w1v.z + cv.w * w1v.w;
        float4 c3;
        c3.x = cv.x * w3v.x; c3.y = cv.y * w3v.y;
        c3.z = cv.z * w3v.z; c3.w = cv.w * w3v.w;
        *(float4*)&cw3s[wid][lane * 4] = c3;
#pragma unroll
        for (int o = 32; o >= 1; o >>= 1) cw1p += __shfl_xor(cw1p, o, 64);
        __syncthreads();
        float s = cw1p + qw2r;
#pragma unroll 8
        for (int h4 = 0; h4 < 64; h4++) {
            float4 c3v = *(const float4*)&cw3s[wid][h4 * 4];
            bf16x4 qb = qlds[lane * 64 + (h4 ^ (lane & 15))];
            s += c3v.x * (float)qb[0] + c3v.y * (float)qb[1]
               + c3v.z * (float)qb[2] + c3v.w * (float)qb[3];
        }
        float mx = s;
#pragma unroll
        for (int o = 32; o >= 1; o >>= 1) mx = fmaxf(mx, __shfl_xor(mx, o, 64));
        if (lane == 0) mrow[b * LCc + i] = mx;
        float pe = __expf(s - mx);
        float den = pe;
#pragma unroll
        for (int o = 32; o >= 1; o >>= 1) den += __shfl_xor(den, o, 64);
        awave[wid][lane] = pe / den;
        __syncthreads();
        float4 accv = {0.f, 0.f, 0.f, 0.f};
#pragma unroll 8
        for (int j = 0; j < 64; j++) {
            float aj = awave[wid][j];
            bf16x4 qb = qlds[j * 64 + (lane ^ (j & 15))];
            accv.x = fmaf(aj, (float)qb[0], accv.x);
            accv.y = fmaf(aj, (float)qb[1], accv.y);
            accv.z = fmaf(aj, (float)qb[2], accv.z);
            accv.w = fmaf(aj, (float)qb[3], accv.w);
        }
        *(float4*)&c2q[((long)b * LCc + i) * Hd + lane * 4] = accv;
        __syncthreads();
    }
}

// ---------- q2c: 128 blocks = 16 b x 8 h-chunks ----------
__global__ __launch_bounds__(256) void k_q2c(const float* __restrict__ ctx,
                                             const float* __restrict__ mrow,
                                             float* __restrict__ q2c) {
    __shared__ float wbuf[LCc];
    __shared__ float red[8];
    __shared__ float part[8][32];
    int blk = blockIdx.x;
    int b = blk >> 3, hc = blk & 7;
    int tid = threadIdx.x;
    float v0 = mrow[b * LCc + tid], v1 = mrow[b * LCc + 256 + tid];
    float m = fmaxf(v0, v1);
#pragma unroll
    for (int o = 32; o >= 1; o >>= 1) m = fmaxf(m, __shfl_xor(m, o, 64));
    if ((tid & 63) == 0) red[tid >> 6] = m;
    __syncthreads();
    float M = fmaxf(fmaxf(red[0], red[1]), fmaxf(red[2], red[3]));
    float e0 = __expf(v0 - M), e1v = __expf(v1 - M);
    float sm = e0 + e1v;
#pragma unroll
    for (int o = 32; o >= 1; o >>= 1) sm += __shfl_xor(sm, o, 64);
    if ((tid & 63) == 0) red[4 + (tid >> 6)] = sm;
    __syncthreads();
    float S = red[4] + red[5] + red[6] + red[7];
    wbuf[tid] = e0 / S;
    wbuf[tid + 256] = e1v / S;
    __syncthreads();
    int ig = tid >> 5, h31 = tid & 31;
    int h = hc * 32 + h31;
    float acc = 0.f;
#pragma unroll 4
    for (int ii = 0; ii < 64; ii++) {
        int i = ig * 64 + ii;
        acc = fmaf(wbuf[i], ctx[((long)b * LCc + i) * Hd + h], acc);
    }
    part[ig][h31] = acc;
    __syncthreads();
    if (tid < 32) {
        float s = 0.f;
#pragma unroll
        for (int k = 0; k < 8; k++) s += part[k][tid];
        q2c[b * Hd + hc * 32 + tid] = s;
    }
}

// ---------- x = [ctx, c2q, ctx*c2q, ctx*q2c] -> bf16 [8192][1024] ----------
__global__ __launch_bounds__(256) void k_buildx(const float* __restrict__ ctx,
                                                const float* __restrict__ c2q,
                                                const float* __restrict__ q2c,
                                                bf16_t* __restrict__ xb) {
    long r = blockIdx.x;
    int b = (int)(r >> 9);
    int tid = threadIdx.x;
    int sec = tid >> 6, h4 = tid & 63;
    float4 cv = *(const float4*)&ctx[r * Hd + h4 * 4];
    float4 v;
    if (sec == 0) {
        v = cv;
    } else if (sec == 1) {
        v = *(const float4*)&c2q[r * Hd + h4 * 4];
    } else if (sec == 2) {
        float4 q = *(const float4*)&c2q[r * Hd + h4 * 4];
        v.x = cv.x * q.x; v.y = cv.y * q.y; v.z = cv.z * q.z; v.w = cv.w * q.w;
    } else {
        float4 q = *(const float4*)&q2c[b * Hd + h4 * 4];
        v.x = cv.x * q.x; v.y = cv.y * q.y; v.z = cv.z * q.z; v.w = cv.w * q.w;
    }
    bf16x4 bv = {(bf16_t)v.x, (bf16_t)v.y, (bf16_t)v.z, (bf16_t)v.w};
    *(bf16x4*)&xb[r * Dd + sec * Hd + h4 * 4] = bv;
}

// ---------- g-column + T pad-zero ----------
__global__ __launch_bounds__(256) void k_gcol(const bf16_t* __restrict__ e1,
                                              const float* __restrict__ Wb,
                                              bf16_t* __restrict__ T) {
    int tid = threadIdx.x;
    int wv = tid >> 6, lane = tid & 63;
    long r = (long)blockIdx.x * 4 + wv;
    bf16x8 ea = *(const bf16x8*)&e1[r * KP + lane * 16];
    bf16x8 eb = *(const bf16x8*)&e1[r * KP + lane * 16 + 8];
    const float* wr0 = Wb + (long)3072 * DP1;   // row block i=1024
#pragma unroll
    for (int c = 0; c < 3; c++) {
        const float* wr = wr0 + (long)c * DP1 + lane * 16;
        float acc = 0.f;
#pragma unroll
        for (int k = 0; k < 8; k++) {
            acc = fmaf((float)ea[k], wr[k], acc);
            acc = fmaf((float)eb[k], wr[8 + k], acc);
        }
#pragma unroll
        for (int o = 32; o >= 1; o >>= 1) acc += __shfl_xor(acc, o, 64);
        long rowb = (r * 3 + c) * (long)KP;
        if (lane == 0)
            T[rowb + 1024] = (bf16_t)(acc + wr0[(long)c * DP1 + 1024]);
        for (int jj = 1025 + lane; jj < KP; jj += 64)
            T[rowb + jj] = (bf16_t)0.f;
    }
}

// ---------- unified 8-phase counted-vmcnt GEMM: tile 256 x (64*NFR), BK=64 ----------
// Read-issues for phases b/c hoisted into preceding MFMA clusters (buffer-safe).
// MODE 0 (FFW1): A=xb, B=W1c, NT=16, NFR=2, grid 256
// MODE 1 (FFW2): A=hbuf+z*512, B=W2c+z*512K, NT=8, NFR=4, grid 256
// MODE 2 (Tcore): A=e1, B=Wbt, NT=18, NFR=3, grid 512 (2 full rounds)
// MODE 3 (out):  A=s1_z, B=T_z, NT=18, NFR=3, grid 256
template <int NT, int NFR, int MODE>
__global__ __launch_bounds__(512) void gemm8p(
    const bf16_t* __restrict__ A, const bf16_t* __restrict__ B,
    const float* __restrict__ b0, const float* __restrict__ b1,
    void* __restrict__ C0, void* __restrict__ C1) {
    constexpr int LDA = (MODE <= 1) ? 1024 : KP;
    constexpr int LDB = (MODE == 0) ? 1024 : (MODE == 1) ? 512 : KP;
    constexpr int BEn = (NFR + 1) / 2;
    constexpr int BOn = NFR / 2;
    constexpr int NCOL = 64 * NFR;
    __shared__ char smem[65536 + NFR * 16384];   // A 2x16K dbuf | B 2xNFR*8K dbuf
    int tid = threadIdx.x;
    int wg = blockIdx.x;
    int xcd = wg & 7, idx = wg >> 3;
    int bx, by, z = 0;
    if (MODE == 0) {
        bx = (xcd & 3) * 8 + (idx & 7); by = (xcd >> 2) * 4 + (idx >> 3);
    } else if (MODE == 1) {
        z = idx >> 4; bx = (xcd & 3) * 8 + (idx & 7); by = (xcd >> 2) * 2 + ((idx >> 3) & 1);
    } else if (MODE == 2) {
        bx = (xcd & 3) * 8 + (idx & 7); by = (xcd >> 2) * 8 + (idx >> 3);
    } else {
        z = xcd * 2 + (idx >> 4); bx = idx & 1; by = (idx >> 1) & 7;
    }
    const bf16_t* At;
    const bf16_t* Bt;
    if (MODE == 0) {
        At = A + (long)bx * 256 * LDA;            Bt = B + (long)by * NCOL * LDB;
    } else if (MODE == 1) {
        At = A + (long)z * 512 + (long)bx * 256 * LDA;
        Bt = B + (long)z * 524288 + (long)by * NCOL * LDB;
    } else if (MODE == 2) {
        At = A + (long)bx * 256 * LDA;            Bt = B + (long)by * NCOL * LDB;
    } else {
        At = A + ((long)z * 512 + bx * 256) * LDA;
        Bt = B + ((long)z * 1536 + by * NCOL) * LDB;
    }
    int lane = tid & 63, wv = tid >> 6, wm = wv >> 2, wn = wv & 3;
    int fr = lane & 15, kg = lane >> 4;
    int row0 = tid >> 3, sc0 = (tid & 7) ^ (row0 & 7);
    int q1 = tid + 512;
    int row1 = q1 >> 3, sc1 = (q1 & 7) ^ (row1 & 7);

    auto stageA = [&](int half, int tile) {
        int ts = tile <= NT - 1 ? tile : NT - 1;   // clamp source
        int buf = tile & 1;
        long rb = (long)half * 128;
        const bf16_t* g0 = At + (rb + row0) * LDA + ts * 64 + sc0 * 8;
        const bf16_t* g1 = At + (rb + row1) * LDA + ts * 64 + sc1 * 8;
        char* l = smem + buf * 32768 + half * 16384;
        gload_lds16(g0, l + tid * 16);
        gload_lds16(g1, l + 8192 + tid * 16);
    };
    auto stageB = [&](int j, int tile) {          // one 64-row call
        int ts = tile <= NT - 1 ? tile : NT - 1;
        int buf = tile & 1;
        const bf16_t* g0 = Bt + (long)(j * 64 + row0) * LDB + ts * 64 + sc0 * 8;
        char* l = smem + 65536 + buf * (NFR * 8192) + j * 8192;
        gload_lds16(g0, l + tid * 16);
    };
    auto RDA = [&](int buf, int h, int m, int kk) -> bf16x8 {
        int row = wm * 128 + h * 64 + m * 16 + fr;
        int c16 = kk * 4 + kg;
        int off = buf * 32768 + row * 128 + ((c16 ^ (row & 7)) << 4);
        return *(const bf16x8*)(smem + off);
    };
    auto RDB = [&](int buf, int n, int kk) -> bf16x8 {
        int row = wn * (16 * NFR) + n * 16 + fr;
        int c16 = kk * 4 + kg;
        int off = 65536 + buf * (NFR * 8192) + row * 128 + ((c16 ^ (row & 7)) << 4);
        return *(const bf16x8*)(smem + off);
    };

    f32x4 acc[8][NFR] = {};

    // prologue: T0 A(4 calls) + T0 B(NFR) + T1 A(4); leave last 4 (T1-A) in flight
    stageA(0, 0); stageA(1, 0);
#pragma unroll
    for (int j = 0; j < NFR; j++) stageB(j, 0);
    stageA(0, 1); stageA(1, 1);
    asm volatile("s_waitcnt vmcnt(4)" ::: "memory");
    __builtin_amdgcn_s_barrier();

    auto doTile = [&](int buf, int sB, int sA) {
        bf16x8 aL[4][2], aH[4][2], bE[BEn][2], bO[BOn][2];
        // phase a: read aL+bE, stage B-even; MFMA (h0,even) with bO reads hidden
#pragma unroll
        for (int m = 0; m < 4; m++)
#pragma unroll
            for (int k = 0; k < 2; k++) aL[m][k] = RDA(buf, 0, m, k);
#pragma unroll
        for (int n = 0; n < BEn; n++)
#pragma unroll
            for (int k = 0; k < 2; k++) bE[n][k] = RDB(buf, n, k);
#pragma unroll
        for (int j = 0; j < BEn; j++) stageB(j, sB);
        __builtin_amdgcn_s_barrier();
        __builtin_amdgcn_s_setprio(1);
#pragma unroll
        for (int n = 0; n < BOn; n++)      // hidden under MFMA cluster (B-buf stable)
#pragma unroll
            for (int k = 0; k < 2; k++) bO[n][k] = RDB(buf, BEn + n, k);
#pragma unroll
        for (int m = 0; m < 4; m++)
#pragma unroll
            for (int n = 0; n < BEn; n++)
#pragma unroll
                for (int k = 0; k < 2; k++)
                    acc[m][n] = __builtin_amdgcn_mfma_f32_16x16x32_bf16(
                        aL[m][k], bE[n][k], acc[m][n], 0, 0, 0);
        __builtin_amdgcn_s_setprio(0);
        __builtin_amdgcn_s_barrier();
        // phase b: stage B-odd; MFMA (h0,odd) with aH reads hidden
#pragma unroll
        for (int j = BEn; j < NFR; j++) stageB(j, sB);
        __builtin_amdgcn_s_barrier();
        __builtin_amdgcn_s_setprio(1);
#pragma unroll
        for (int m = 0; m < 4; m++)        // hidden (A-buf half1 untouched until phase d)
#pragma unroll
            for (int k = 0; k < 2; k++) aH[m][k] = RDA(buf, 1, m, k);
#pragma unroll
        for (int m = 0; m < 4; m++)
#pragma unroll
            for (int n = 0; n < BOn; n++)
#pragma unroll
                for (int k = 0; k < 2; k++)
                    acc[m][BEn + n] = __builtin_amdgcn_mfma_f32_16x16x32_bf16(
                        aL[m][k], bO[n][k], acc[m][BEn + n], 0, 0, 0);
        __builtin_amdgcn_s_setprio(0);
        __builtin_amdgcn_s_barrier();
        // phase c: stage A0(sA); MFMA (h1,even)
        stageA(0, sA);
        __builtin_amdgcn_s_barrier();
        __builtin_amdgcn_s_setprio(1);
#pragma unroll
        for (int m = 0; m < 4; m++)
#pragma unroll
            for (int n = 0; n < BEn; n++)
#pragma unroll
                for (int k = 0; k < 2; k++)
                    acc[4 + m][n] = __builtin_amdgcn_mfma_f32_16x16x32_bf16(
                        aH[m][k], bE[n][k], acc[4 + m][n], 0, 0, 0);
        __builtin_amdgcn_s_setprio(0);
        __builtin_amdgcn_s_barrier();
        // phase d: stage A1(sA); MFMA (h1,odd); counted vmcnt; barrier
        stageA(1, sA);
        __builtin_amdgcn_s_barrier();
        __builtin_amdgcn_s_setprio(1);
#pragma unroll
        for (int m = 0; m < 4; m++)
#pragma unroll
            for (int n = 0; n < BOn; n++)
#pragma unroll
                for (int k = 0; k < 2; k++)
                    acc[4 + m][BEn + n] = __builtin_amdgcn_mfma_f32_16x16x32_bf16(
                        aH[m][k], bO[n][k], acc[4 + m][BEn + n], 0, 0, 0);
        __builtin_amdgcn_s_setprio(0);
        asm volatile("s_waitcnt vmcnt(4)" ::: "memory");
        __builtin_amdgcn_s_barrier();
    };

    for (int it = 0; it < NT / 2; ++it) {
        int t = 2 * it;
        doTile(0, t + 1, t + 2);
        doTile(1, t + 2, t + 3);
    }

    // epilogue
#pragma unroll
    for (int mf = 0; mf < 8; mf++) {
#pragma unroll
        for (int g = 0; g < 4; g++) {
            int rloc = wm * 128 + mf * 16 + kg * 4 + g;
            long r = (long)bx * 256 + rloc;
#pragma unroll
            for (int nf = 0; nf < NFR; nf++) {
                int col = wn * (16 * NFR) + nf * 16 + fr;
                float v = acc[mf][nf][g];
                if (MODE == 0) {
                    int colg = by * NCOL + col;
                    v += (colg < 512) ? b0[colg] : b1[colg - 512];
                    v = fmaxf(v, 0.f);
                    ((bf16_t*)C0)[r * 1024 + colg] = (bf16_t)v;
                } else if (MODE == 1) {
                    int colg = by * NCOL + col;
                    v += z ? b1[colg] : b0[colg];
                    ((bf16_t*)(z ? C1 : C0))[r * (long)KP + colg] = (bf16_t)v;
                } else if (MODE == 2) {
                    int colg = by * NCOL + col;
                    int cls = colg >> 10, i = colg & 1023;
                    ((bf16_t*)C0)[(r * 3 + cls) * (long)KP + i] = (bf16_t)v;
                } else {
                    int colg = by * NCOL + col;
                    ((float*)C0)[(long)z * (512L * YC) + r * YC + colg] = v;
                }
            }
        }
    }
}

extern "C" void kernel_launch(void* const* d_in, const int* in_sizes, int n_in,
                              void* d_out, int out_size, void* d_ws, size_t ws_size,
                              hipStream_t stream) {
    const float* ctx  = (const float*)d_in[0];
    const float* ques = (const float*)d_in[1];
    const float* wsim = (const float*)d_in[2];
    const float* W1s  = (const float*)d_in[3];
    const float* b1s  = (const float*)d_in[4];
    const float* W2s  = (const float*)d_in[5];
    const float* b2s  = (const float*)d_in[6];
    const float* W1e  = (const float*)d_in[7];
    const float* b1e  = (const float*)d_in[8];
    const float* W2e  = (const float*)d_in[9];
    const float* b2e  = (const float*)d_in[10];
    const float* Wb   = (const float*)d_in[11];

    char* ws = (char*)d_ws;
    float*  qw2  = (float*)(ws + OFF_QW2);
    float*  mrow = (float*)(ws + OFF_MROW);
    float*  q2c  = (float*)(ws + OFF_Q2C);
    float*  c2q  = (float*)(ws + OFF_C2Q);
    bf16_t* xb   = (bf16_t*)(ws + OFF_XB);
    bf16_t* hbuf = (bf16_t*)(ws + OFF_HBUF);
    bf16_t* W1c  = (bf16_t*)(ws + OFF_W1C);
    bf16_t* W2c  = (bf16_t*)(ws + OFF_W2C);
    bf16_t* T    = (bf16_t*)(ws + OFF_T);
    bf16_t* s1   = (bf16_t*)(ws + OFF_S1);
    bf16_t* e1   = (bf16_t*)(ws + OFF_E1);
    bf16_t* Wbt  = (bf16_t*)(ws + OFF_WBT);

    // weight prep + attention front-end
    k_qw2<<<256, 256, 0, stream>>>(ques, wsim, qw2);
    k_wtrans2<<<dim3(32, 16, 2), 256, 0, stream>>>(W1s, W1e, W1c, 1024, 512);
    k_wtrans2<<<dim3(16, 32, 2), 256, 0, stream>>>(W2s, W2e, W2c, 512, 1024);
    k_wb<<<3072, 256, 0, stream>>>(Wb, Wbt);
    k_attn<<<Bsz * 32, 256, 0, stream>>>(ctx, ques, wsim, qw2, c2q, mrow);
    k_q2c<<<128, 256, 0, stream>>>(ctx, mrow, q2c);
    k_buildx<<<NROW, 256, 0, stream>>>(ctx, c2q, q2c, xb);
    k_initse<<<4096, 256, 0, stream>>>(s1, e1);

    // FFW1: hbuf = relu(x@[W1s|W1e] + [b1s|b1e])  (256x128 tiles, grid 256)
    gemm8p<16, 2, 0><<<256, 512, 0, stream>>>(xb, W1c, b1s, b1e, hbuf, nullptr);
    // FFW2: {s1,e1} = h_z @ W2z + b2z             (256x256 tiles, grid 256)
    gemm8p<8, 4, 1><<<256, 512, 0, stream>>>(hbuf, W2c, b2s, b2e, s1, e1);
    // g-column of T (i = 1024) + zero T pad cols
    k_gcol<<<2048, 256, 0, stream>>>(e1, Wb, T);
    // T core: [8192x3072] = e1 @ Wbt^T            (256x192 tiles, grid 512 = 2 rounds)
    gemm8p<18, 3, 2><<<512, 512, 0, stream>>>(e1, Wbt, nullptr, nullptr, T, nullptr);
    // out = s1 @ T^T per batch                    (256x192 tiles, grid 256)
    gemm8p<18, 3, 3><<<256, 512, 0, stream>>>(s1, T, nullptr, nullptr, d_out, nullptr);
}